// Round 10
// baseline (159.555 us; speedup 1.0000x reference)
//
#include <hip/hip_runtime.h>

// Problem constants: T=16, H=1280, W=1280, N=64 boxes.
#define TT 16
#define HH 1280
#define WW 1280
#define NBOX 64
#define W4 (WW / 4)                  // 320 float4 per row
#define SLICE4 (HH * W4)             // 409600 float4 per T-slice
#define CHUNK 4096                   // float4 per block (64 KB contiguous)
#define NBLK (TT * SLICE4 / CHUNK)   // 1600 blocks; 100 per slice exactly

#define GLOBAL_AS __attribute__((address_space(1)))
#define LDS_AS    __attribute__((address_space(3)))

// K1: row/col membership bitmasks (parallel, 10 blocks, ~3 us).
__global__ void build_masks_kernel(const int* __restrict__ boxes,
                                   unsigned long long* __restrict__ rowmask,
                                   unsigned long long* __restrict__ colmask) {
    __shared__ int bx1[NBOX], by1[NBOX], bx2[NBOX], by2[NBOX];
    int tid = threadIdx.x;
    if (tid < NBOX) {
        int4 b = ((const int4*)boxes)[tid];   // (x1, y1, x2, y2)
        bx1[tid] = b.x; by1[tid] = b.y; bx2[tid] = b.z; by2[tid] = b.w;
    }
    __syncthreads();
    int g = blockIdx.x * 256 + tid;           // 0..2559
    if (g < HH) {
        int y = g;
        unsigned long long m = 0ull;
#pragma unroll
        for (int b = 0; b < NBOX; ++b)
            if (by1[b] <= y && y < by2[b]) m |= (1ull << b);
        rowmask[y] = m;
    } else if (g < HH + WW) {
        int x = g - HH;
        unsigned long long m = 0ull;
#pragma unroll
        for (int b = 0; b < NBOX; ++b)
            if (bx1[b] <= x && x < bx2[b]) m |= (1ull << b);
        colmask[x] = m;
    }
}

// K2: per-site weight map, uchar4 per (y,x4) site (1600 blocks, ~5 us).
__global__ void __launch_bounds__(256)
build_wmap_kernel(const unsigned long long* __restrict__ rowmask,
                  const unsigned long long* __restrict__ colmask,
                  uchar4* __restrict__ wmap) {
    int idx = blockIdx.x * 256 + threadIdx.x; // exactly SLICE4 threads
    int y  = idx / W4;
    int x4 = idx - y * W4;
    unsigned long long rm = rowmask[y];
    int x = x4 * 4;
    uchar4 w;
    w.x = (unsigned char)__popcll(rm & colmask[x + 0]);
    w.y = (unsigned char)__popcll(rm & colmask[x + 1]);
    w.z = (unsigned char)__popcll(rm & colmask[x + 2]);
    w.w = (unsigned char)__popcll(rm & colmask[x + 3]);
    wmap[idx] = w;
}

// K3: THE experiment -- direct-to-LDS streaming (global_load_lds, width=16).
// A VGPR-destination load queue collapses to ~100 outstanding lines/CU
// (R0-R9 plateau at ~1.8 TB/s). global_load_lds has no VGPR destination:
// each wave keeps 16 x 1KB transfers in flight at zero register cost.
// Geometry identical to R7 (proven absmax=0): block b owns contiguous
// 64 KB chunk; wave w stages its 16 KB quarter; no __syncthreads needed
// (each wave consumes only its own LDS region after a per-wave vmcnt drain).
__global__ void __launch_bounds__(256)
lds_stream_kernel(const float4* __restrict__ data,
                  const uchar4* __restrict__ wmap,
                  float* __restrict__ out) {
    __shared__ float4 stage[CHUNK];           // 64 KB -> 2 blocks/CU
    const int tid  = threadIdx.x;
    const int lane = tid & 63;
    const int wv   = tid >> 6;                // wave 0..3
    const int blk  = blockIdx.x;              // 0..1599
    const int t    = blk / 100;               // slice id
    const int sbase = (blk - t * 100) * CHUNK;

    const float4* chunk = data + blk * CHUNK;

    // Weights for this wave's quarter: 16 uchar4 per lane, issued before the
    // staging DMA so their latency overlaps it.
    const uchar4* wp = wmap + sbase + wv * 1024;
    uchar4 wb[16];
#pragma unroll
    for (int j = 0; j < 16; ++j)
        wb[j] = wp[j * 64 + lane];

    // Wave wv stages local float4 indices [wv*1024, wv*1024+1024) in 16 calls.
    // LDS dest is wave-uniform; HW scatters lane l to base + l*16.
#pragma unroll
    for (int i = 0; i < 16; ++i) {
        const float4* src = chunk + wv * 1024 + i * 64 + lane;
        __builtin_amdgcn_global_load_lds(
            (const GLOBAL_AS void*)src,
            (LDS_AS void*)&stage[wv * 1024 + i * 64],
            16, 0, 0);
    }
    __builtin_amdgcn_s_waitcnt(0);            // per-wave drain (vmcnt+lgkm)
    __builtin_amdgcn_sched_barrier(0);        // pin: no motion across the wait

    float a0 = 0.f, a1 = 0.f, a2 = 0.f, a3 = 0.f;
#pragma unroll
    for (int j = 0; j < 16; ++j) {
        float4 v = stage[wv * 1024 + j * 64 + lane];  // b128, 16B lane stride
        a0 += v.x * (float)wb[j].x;
        a1 += v.y * (float)wb[j].y;
        a2 += v.z * (float)wb[j].z;
        a3 += v.w * (float)wb[j].w;
    }
    float acc = (a0 + a1) + (a2 + a3);

    // 64-lane wave shuffle reduction -> LDS -> one atomic per block.
#pragma unroll
    for (int off = 32; off > 0; off >>= 1)
        acc += __shfl_down(acc, off, 64);

    __shared__ float wsum[4];
    if (lane == 0) wsum[wv] = acc;
    __syncthreads();
    if (tid == 0) {
        float s = (wsum[0] + wsum[1]) + (wsum[2] + wsum[3]);
        atomicAdd(out, s);
    }
}

extern "C" void kernel_launch(void* const* d_in, const int* in_sizes, int n_in,
                              void* d_out, int out_size, void* d_ws, size_t ws_size,
                              hipStream_t stream) {
    const float* data = (const float*)d_in[0];        // (T,H,W) float32
    const int* boxes  = (const int*)d_in[1];          // (N,4) int32
    float* out = (float*)d_out;                       // scalar (poisoned 0xAA)

    // d_ws: rowmask[1280] u64, colmask[1280] u64, wmap[409600] uchar4.
    unsigned long long* rowmask = (unsigned long long*)d_ws;
    unsigned long long* colmask = rowmask + HH;
    uchar4* wmap = (uchar4*)(colmask + WW);

    hipMemsetAsync(out, 0, sizeof(float), stream);
    build_masks_kernel<<<10, 256, 0, stream>>>(boxes, rowmask, colmask);
    build_wmap_kernel<<<SLICE4 / 256, 256, 0, stream>>>(rowmask, colmask, wmap);
    lds_stream_kernel<<<NBLK, 256, 0, stream>>>(
        (const float4*)data, wmap, out);
}